// Round 4
// baseline (239.442 us; speedup 1.0000x reference)
//
#include <hip/hip_runtime.h>
#include <hip/hip_bf16.h>

#define S_LEN 4096
#define BATCH 4
#define DMODEL 1024
#define HDIM 128
#define NSLOT 4   // KV chunks per q-tile (equal split of the causal range)

typedef __attribute__((ext_vector_type(8))) short short8;
typedef __attribute__((ext_vector_type(4))) short short4v;
typedef __attribute__((ext_vector_type(4))) float float4v;
typedef __attribute__((ext_vector_type(16))) float float16v;
typedef __attribute__((ext_vector_type(4))) int int4v;

#define MASKVAL (-3.0e38f)
#define MINIT   (-1.0e30f)

static __device__ __forceinline__ unsigned short f2bf(float f) {
    __hip_bfloat16 h = __float2bfloat16(f);
    return *reinterpret_cast<unsigned short*>(&h);
}
static __device__ __forceinline__ unsigned short f2h(float f) {
    _Float16 h = (_Float16)f; return *reinterpret_cast<unsigned short*>(&h);
}
static __device__ __forceinline__ float h2f(unsigned short u) {
    _Float16 h = *reinterpret_cast<_Float16*>(&u); return (float)h;
}

// ---------------------------------------------------------------------------
// Kernel A: QKV projection, per-batch tiled.  For which=0/1 writes (B,S,H);
// for which=2 (V) swaps MFMA operands and writes V^T as (B,H,S).
// ---------------------------------------------------------------------------
__global__ __launch_bounds__(256) void qkv_proj_kernel(
    const float* __restrict__ x, const float* __restrict__ Wq,
    const float* __restrict__ Wk, const float* __restrict__ Wv,
    unsigned short* __restrict__ Qb, unsigned short* __restrict__ Kb,
    unsigned short* __restrict__ Vtb)
{
    __shared__ unsigned short As[128 * 72];
    __shared__ unsigned short Bs[128 * 72];

    const int t = threadIdx.x;
    const int s0 = blockIdx.x * 128;
    const int b = blockIdx.y;
    const int which = blockIdx.z;
    const float* W = (which == 0) ? Wq : (which == 1) ? Wk : Wv;

    const int lane = t & 63;
    const int w = t >> 6;
    const int wr = (w >> 1) * 64;
    const int wc = (w & 1) * 64;
    const int l15 = lane & 15;
    const int l4 = lane >> 4;

    float4v acc[4][4];
#pragma unroll
    for (int i = 0; i < 4; i++)
#pragma unroll
        for (int j = 0; j < 4; j++) acc[i][j] = (float4v){0.f, 0.f, 0.f, 0.f};

    const int krow = t >> 4;
    const int kcol4 = (t & 15) * 4;

    for (int k0 = 0; k0 < DMODEL; k0 += 64) {
        __syncthreads();
#pragma unroll
        for (int p = 0; p < 8; p++) {
            int row = p * 16 + krow;
            float4 v = *reinterpret_cast<const float4*>(
                &x[((size_t)(s0 + row) * BATCH + b) * DMODEL + k0 + kcol4]);
            short4v h;
            h[0] = (short)f2bf(v.x); h[1] = (short)f2bf(v.y);
            h[2] = (short)f2bf(v.z); h[3] = (short)f2bf(v.w);
            *reinterpret_cast<short4v*>(&As[row * 72 + kcol4]) = h;
        }
#pragma unroll
        for (int p = 0; p < 8; p++) {
            int row = p * 16 + krow;
            float4 v = *reinterpret_cast<const float4*>(
                &W[(size_t)row * DMODEL + k0 + kcol4]);
            short4v h;
            h[0] = (short)f2bf(v.x); h[1] = (short)f2bf(v.y);
            h[2] = (short)f2bf(v.z); h[3] = (short)f2bf(v.w);
            *reinterpret_cast<short4v*>(&Bs[row * 72 + kcol4]) = h;
        }
        __syncthreads();

#pragma unroll
        for (int kk = 0; kk < 64; kk += 32) {
            short8 a[4], bfr[4];
#pragma unroll
            for (int mi = 0; mi < 4; mi++)
                a[mi] = *reinterpret_cast<const short8*>(
                    &As[(wr + mi * 16 + l15) * 72 + kk + l4 * 8]);
#pragma unroll
            for (int ni = 0; ni < 4; ni++)
                bfr[ni] = *reinterpret_cast<const short8*>(
                    &Bs[(wc + ni * 16 + l15) * 72 + kk + l4 * 8]);
            if (which != 2) {
#pragma unroll
                for (int mi = 0; mi < 4; mi++)
#pragma unroll
                    for (int ni = 0; ni < 4; ni++)
                        acc[mi][ni] = __builtin_amdgcn_mfma_f32_16x16x32_bf16(
                            a[mi], bfr[ni], acc[mi][ni], 0, 0, 0);
            } else {
#pragma unroll
                for (int mi = 0; mi < 4; mi++)
#pragma unroll
                    for (int ni = 0; ni < 4; ni++)
                        acc[mi][ni] = __builtin_amdgcn_mfma_f32_16x16x32_bf16(
                            bfr[ni], a[mi], acc[mi][ni], 0, 0, 0);
            }
        }
    }

    if (which != 2) {
        unsigned short* Out = (which == 0) ? Qb : Kb;
        const float scale = (which == 0) ? 0.08838834764831845f : 1.0f;
#pragma unroll
        for (int mi = 0; mi < 4; mi++)
#pragma unroll
            for (int ni = 0; ni < 4; ni++)
#pragma unroll
                for (int r = 0; r < 4; r++) {
                    int s = s0 + wr + mi * 16 + l4 * 4 + r;
                    int h = wc + ni * 16 + l15;
                    Out[((size_t)b * S_LEN + s) * HDIM + h] =
                        f2bf(acc[mi][ni][r] * scale);
                }
    } else {
#pragma unroll
        for (int mi = 0; mi < 4; mi++)
#pragma unroll
            for (int ni = 0; ni < 4; ni++)
#pragma unroll
                for (int r = 0; r < 4; r++) {
                    int h = wc + ni * 16 + l4 * 4 + r;
                    int s = s0 + wr + mi * 16 + l15;
                    Vtb[((size_t)b * HDIM + h) * S_LEN + s] = f2bf(acc[mi][ni][r]);
                }
    }
}

// ---------------------------------------------------------------------------
// Kernel B: causal flash attention, swapped-QK 32x32 MFMA, in-register softmax.
// 4 waves x QBLK=32 q rows = 128 q rows per block.  KVBLK=64.
// Each block: (qtile, batch, chunk c of NSLOT equal KV chunks).
// Writes normalized fp16 partial O + per-row (m, l).
// ---------------------------------------------------------------------------
__global__ __launch_bounds__(256) void attn_kernel(
    const unsigned short* __restrict__ Qb, const unsigned short* __restrict__ Kb,
    const unsigned short* __restrict__ Vtb, unsigned short* __restrict__ Opart,
    float* __restrict__ Mpart, float* __restrict__ Lpart)
{
    __shared__ unsigned short Ks[64 * 128];    // [kv][d], row-swizzled
    __shared__ unsigned short Vs[128 * 64];    // [h][kv], row-swizzled

    const int t = threadIdx.x;
    const int w = t >> 6;             // wave 0..3
    const int lane = t & 63;
    const int l31 = lane & 31;
    const int hi = lane >> 5;         // 0/1 half
    const int b = blockIdx.y;
    const int c = blockIdx.z;
    const int qt = 31 - blockIdx.x;   // big tiles first

    const int nkv = 2 * (qt + 1);
    const int csize = (nkv + NSLOT - 1) / NSLOT;
    const int lo = c * csize;
    const int hic = min(lo + csize, nkv);
    if (lo >= hic) return;

    const int qb = qt * 128;
    const int qrow = qb + w * 32 + l31;       // this lane's q (col of S^T)
    const size_t base = (size_t)b * S_LEN * HDIM;

    // Q as B-fragments: qf[f] = Q[qrow][f*16 + hi*8 .. +7]
    short8 qf[8];
#pragma unroll
    for (int f = 0; f < 8; f++)
        qf[f] = *reinterpret_cast<const short8*>(
            &Qb[base + (size_t)qrow * HDIM + f * 16 + hi * 8]);

    float m_run = MINIT, l_run = 0.f;
    float16v o[4];                    // O^T: rows h (4 blocks of 32), col q
#pragma unroll
    for (int hb = 0; hb < 4; hb++)
#pragma unroll
        for (int r = 0; r < 16; r++) o[hb][r] = 0.f;

    // staging assignments (256 threads; K 64x128, V^T 128x64, 4 uint4 each)
    const int kr = t >> 2, kc = (t & 3) * 32;
    const int vh = t >> 1, vc = (t & 1) * 32;
    uint4 kreg[4], vreg[4];
    {
        int kvb = lo * 64;
        const unsigned short* kp = &Kb[base + (size_t)(kvb + kr) * HDIM + kc];
#pragma unroll
        for (int j = 0; j < 4; j++)
            kreg[j] = *reinterpret_cast<const uint4*>(kp + j * 8);
        const unsigned short* vp = &Vtb[((size_t)b * HDIM + vh) * S_LEN + kvb + vc];
#pragma unroll
        for (int j = 0; j < 4; j++)
            vreg[j] = *reinterpret_cast<const uint4*>(vp + j * 8);
    }

    for (int ti = lo; ti < hic; ti++) {
        const int kvb = ti * 64;
        __syncthreads();   // previous iteration's LDS reads done
#pragma unroll
        for (int j = 0; j < 4; j++) {
            int off = (kr * 256 + (kc + j * 8) * 2) ^ ((kr & 7) << 4);
            *reinterpret_cast<uint4*>(reinterpret_cast<char*>(Ks) + off) = kreg[j];
        }
#pragma unroll
        for (int j = 0; j < 4; j++) {
            int off = (vh * 128 + (vc + j * 8) * 2) ^ ((vh & 7) << 4);
            *reinterpret_cast<uint4*>(reinterpret_cast<char*>(Vs) + off) = vreg[j];
        }
        __syncthreads();
        if (ti + 1 < hic) {   // prefetch next tile into regs (hides under MFMA)
            int kvb2 = (ti + 1) * 64;
            const unsigned short* kp = &Kb[base + (size_t)(kvb2 + kr) * HDIM + kc];
#pragma unroll
            for (int j = 0; j < 4; j++)
                kreg[j] = *reinterpret_cast<const uint4*>(kp + j * 8);
            const unsigned short* vp = &Vtb[((size_t)b * HDIM + vh) * S_LEN + kvb2 + vc];
#pragma unroll
            for (int j = 0; j < 4; j++)
                vreg[j] = *reinterpret_cast<const uint4*>(vp + j * 8);
        }

        // S^T = K Q^T (swapped): s0 = kv 0..31, s1 = kv 32..63; col = q
        float16v s0, s1;
#pragma unroll
        for (int r = 0; r < 16; r++) { s0[r] = 0.f; s1[r] = 0.f; }
#pragma unroll
        for (int f = 0; f < 8; f++) {
            int colb = f * 32 + hi * 16;   // byte col = (f*16 + hi*8)*2
            int off0 = (l31 * 256 + colb) ^ ((l31 & 7) << 4);
            int off1 = ((32 + l31) * 256 + colb) ^ ((l31 & 7) << 4);
            short8 k0 = *reinterpret_cast<const short8*>(
                reinterpret_cast<const char*>(Ks) + off0);
            short8 k1 = *reinterpret_cast<const short8*>(
                reinterpret_cast<const char*>(Ks) + off1);
            s0 = __builtin_amdgcn_mfma_f32_32x32x16_bf16(k0, qf[f], s0, 0, 0, 0);
            s1 = __builtin_amdgcn_mfma_f32_32x32x16_bf16(k1, qf[f], s1, 0, 0, 0);
        }

        // causal mask (only tiles touching/above this wave's diagonal band)
        if (kvb + 63 > qb + w * 32) {
#pragma unroll
            for (int r = 0; r < 16; r++) {
                int kv0 = kvb + (r & 3) + 8 * (r >> 2) + 4 * hi;
                if (kv0 > qrow) s0[r] = MASKVAL;
                if (kv0 + 32 > qrow) s1[r] = MASKVAL;
            }
        }

        // in-register softmax over this lane's 32 kv + pair-lane combine
        float pmax = s0[0];
#pragma unroll
        for (int r = 1; r < 16; r++) pmax = fmaxf(pmax, s0[r]);
#pragma unroll
        for (int r = 0; r < 16; r++) pmax = fmaxf(pmax, s1[r]);
        pmax = fmaxf(pmax, __shfl_xor(pmax, 32));
        float mnew = fmaxf(m_run, pmax);
        float alpha = __expf(m_run - mnew);
        m_run = mnew;
#pragma unroll
        for (int r = 0; r < 16; r++) s0[r] = __expf(s0[r] - mnew);
#pragma unroll
        for (int r = 0; r < 16; r++) s1[r] = __expf(s1[r] - mnew);
        float sum = 0.f;
#pragma unroll
        for (int r = 0; r < 16; r++) sum += s0[r] + s1[r];
        sum += __shfl_xor(sum, 32);
        l_run = l_run * alpha + sum;
#pragma unroll
        for (int hb = 0; hb < 4; hb++) o[hb] = o[hb] * alpha;

        // PV: O^T += V^T @ P  (P as B-operand, built in-register per window)
#pragma unroll
        for (int tw = 0; tw < 4; tw++) {
            const int rb = (tw & 1) * 8;
            float pv[8];
#pragma unroll
            for (int j = 0; j < 8; j++)
                pv[j] = (tw < 2) ? ((tw & 1) ? s0[8 + j] : s0[j])
                                 : ((tw & 1) ? s1[8 + j] : s1[j]);
            unsigned int A  = (unsigned int)f2bf(pv[0]) | ((unsigned int)f2bf(pv[1]) << 16);
            unsigned int Bw = (unsigned int)f2bf(pv[2]) | ((unsigned int)f2bf(pv[3]) << 16);
            unsigned int C  = (unsigned int)f2bf(pv[4]) | ((unsigned int)f2bf(pv[5]) << 16);
            unsigned int D  = (unsigned int)f2bf(pv[6]) | ((unsigned int)f2bf(pv[7]) << 16);
            // exchange: each lane sends what its partner needs
            unsigned int y1 = (unsigned int)__shfl_xor((int)(hi ? A : C), 32);
            unsigned int y2 = (unsigned int)__shfl_xor((int)(hi ? Bw : D), 32);
            int4v pw;
            pw[0] = (int)(hi ? y1 : A);
            pw[1] = (int)(hi ? y2 : Bw);
            pw[2] = (int)(hi ? C : y1);
            pw[3] = (int)(hi ? D : y2);
            union { int4v i; short8 s; } pu; pu.i = pw;
#pragma unroll
            for (int hb = 0; hb < 4; hb++) {
                int hrow = hb * 32 + l31;
                int off = (hrow * 128 + tw * 32 + hi * 16) ^ ((hrow & 7) << 4);
                short8 vf = *reinterpret_cast<const short8*>(
                    reinterpret_cast<const char*>(Vs) + off);
                o[hb] = __builtin_amdgcn_mfma_f32_32x32x16_bf16(vf, pu.s, o[hb], 0, 0, 0);
            }
        }
    }

    // epilogue: normalized fp16 partial + (m,l);  l==0 -> zeros (fully masked)
    const size_t R0 = (size_t)(c * BATCH + b) * S_LEN;
    const float inv = (l_run > 0.f) ? 1.f / l_run : 0.f;
#pragma unroll
    for (int hb = 0; hb < 4; hb++)
#pragma unroll
        for (int g = 0; g < 4; g++) {
            int h0 = hb * 32 + g * 8 + hi * 4;
            short4v ov;
#pragma unroll
            for (int j = 0; j < 4; j++)
                ov[j] = (short)f2h(o[hb][g * 4 + j] * inv);
            *reinterpret_cast<short4v*>(&Opart[(R0 + qrow) * HDIM + h0]) = ov;
        }
    if (hi == 0) { Mpart[R0 + qrow] = m_run; Lpart[R0 + qrow] = l_run; }
}

// ---------------------------------------------------------------------------
// Kernel B2: combine partials -> Ob (B,S,H) bf16
// ---------------------------------------------------------------------------
__global__ __launch_bounds__(256) void combine_kernel(
    const unsigned short* __restrict__ Opart, const float* __restrict__ Mpart,
    const float* __restrict__ Lpart, unsigned short* __restrict__ Ob)
{
    const int BS = BATCH * S_LEN;
    int idx = blockIdx.x * 256 + threadIdx.x;
    int r = idx >> 4, hc = (idx & 15) * 8;
    int q = r & (S_LEN - 1);
    int qt = q >> 7;
    int nkv = 2 * (qt + 1);
    int csize = (nkv + NSLOT - 1) / NSLOT;
    int cnt = (nkv + csize - 1) / csize;     // # non-empty chunks

    float m = -INFINITY;
    for (int j = 0; j < cnt; j++) m = fmaxf(m, Mpart[j * BS + r]);
    float wsum = 0.f;
    float acc[8];
#pragma unroll
    for (int e = 0; e < 8; e++) acc[e] = 0.f;
    for (int j = 0; j < cnt; j++) {
        float wj = __expf(Mpart[j * BS + r] - m) * Lpart[j * BS + r];
        wsum += wj;
        short8 o = *reinterpret_cast<const short8*>(
            &Opart[((size_t)j * BS + r) * HDIM + hc]);
#pragma unroll
        for (int e = 0; e < 8; e++) acc[e] += wj * h2f((unsigned short)o[e]);
    }
    float inv = 1.f / wsum;
    short8 ob;
#pragma unroll
    for (int e = 0; e < 8; e++) ob[e] = (short)f2bf(acc[e] * inv);
    *reinterpret_cast<short8*>(&Ob[(size_t)r * HDIM + hc]) = ob;
}

// ---------------------------------------------------------------------------
// Kernel C: output projection, per-batch tiled.
// ---------------------------------------------------------------------------
__global__ __launch_bounds__(256) void out_proj_kernel(
    const unsigned short* __restrict__ Ob, const float* __restrict__ Wo,
    float* __restrict__ out)
{
    __shared__ unsigned short As[128 * 128];
    __shared__ unsigned short Bs[128 * 128];

    const int t = threadIdx.x;
    const int lane = t & 63, w = t >> 6;
    const int l15 = lane & 15, l4 = lane >> 4;
    const int wr = (w >> 1) * 64, wc = (w & 1) * 64;
    const int s0 = blockIdx.x * 128;
    const int d0 = blockIdx.y * 128;
    const int b = blockIdx.z;

#pragma unroll
    for (int p = 0; p < 8; p++) {
        int e = p * 2048 + t * 8;
        int r = e >> 7, h = e & 127;
        short8 v = *reinterpret_cast<const short8*>(
            &Ob[((size_t)b * S_LEN + s0 + r) * HDIM + h]);
        int off = (r * 256 + h * 2) ^ ((r & 7) << 4);
        *reinterpret_cast<short8*>(reinterpret_cast<char*>(As) + off) = v;
    }
#pragma unroll
    for (int p = 0; p < 16; p++) {
        int e = p * 1024 + t * 4;
        int r = e >> 7, h = e & 127;
        float4 v = *reinterpret_cast<const float4*>(&Wo[(size_t)(d0 + r) * HDIM + h]);
        short4v hh;
        hh[0] = (short)f2bf(v.x); hh[1] = (short)f2bf(v.y);
        hh[2] = (short)f2bf(v.z); hh[3] = (short)f2bf(v.w);
        int off = (r * 256 + h * 2) ^ ((r & 7) << 4);
        *reinterpret_cast<short4v*>(reinterpret_cast<char*>(Bs) + off) = hh;
    }
    __syncthreads();

    float4v acc[4][4];
#pragma unroll
    for (int i = 0; i < 4; i++)
#pragma unroll
        for (int j = 0; j < 4; j++) acc[i][j] = (float4v){0.f, 0.f, 0.f, 0.f};

#pragma unroll
    for (int kk = 0; kk < 4; kk++) {
        short8 a[4], bf[4];
#pragma unroll
        for (int mi = 0; mi < 4; mi++) {
            int row = wr + mi * 16 + l15;
            int off = (row * 256 + (kk * 32 + l4 * 8) * 2) ^ ((row & 7) << 4);
            a[mi] = *reinterpret_cast<const short8*>(
                reinterpret_cast<const char*>(As) + off);
        }
#pragma unroll
        for (int ni = 0; ni < 4; ni++) {
            int row = wc + ni * 16 + l15;
            int off = (row * 256 + (kk * 32 + l4 * 8) * 2) ^ ((row & 7) << 4);
            bf[ni] = *reinterpret_cast<const short8*>(
                reinterpret_cast<const char*>(Bs) + off);
        }
#pragma unroll
        for (int mi = 0; mi < 4; mi++)
#pragma unroll
            for (int ni = 0; ni < 4; ni++)
                acc[mi][ni] = __builtin_amdgcn_mfma_f32_16x16x32_bf16(
                    a[mi], bf[ni], acc[mi][ni], 0, 0, 0);
    }

#pragma unroll
    for (int mi = 0; mi < 4; mi++)
#pragma unroll
        for (int ni = 0; ni < 4; ni++)
#pragma unroll
            for (int r = 0; r < 4; r++) {
                int s = s0 + wr + mi * 16 + l4 * 4 + r;
                int d = d0 + wc + ni * 16 + l15;
                out[((size_t)s * BATCH + b) * DMODEL + d] = acc[mi][ni][r];
            }
}

// ---------------------------------------------------------------------------
extern "C" void kernel_launch(void* const* d_in, const int* in_sizes, int n_in,
                              void* d_out, int out_size, void* d_ws, size_t ws_size,
                              hipStream_t stream) {
    const float* x  = (const float*)d_in[0];
    const float* Wq = (const float*)d_in[1];
    const float* Wk = (const float*)d_in[2];
    const float* Wv = (const float*)d_in[3];
    const float* Wo = (const float*)d_in[4];
    float* out = (float*)d_out;

    const size_t elems = (size_t)BATCH * S_LEN * HDIM;     // 2M
    const size_t BS = (size_t)BATCH * S_LEN;               // 16384
    unsigned short* Qb    = (unsigned short*)d_ws;
    unsigned short* Kb    = Qb + elems;
    unsigned short* Vtb   = Kb + elems;
    unsigned short* Ob    = Vtb + elems;
    unsigned short* Opart = Ob + elems;                    // NSLOT*BS*H fp16
    float* Mpart = (float*)(Opart + (size_t)NSLOT * BS * HDIM);
    float* Lpart = Mpart + (size_t)NSLOT * BS;

    qkv_proj_kernel<<<dim3(32, BATCH, 3), 256, 0, stream>>>(x, Wq, Wk, Wv, Qb, Kb, Vtb);
    attn_kernel<<<dim3(32, BATCH, NSLOT), 256, 0, stream>>>(Qb, Kb, Vtb, Opart, Mpart, Lpart);
    combine_kernel<<<dim3(1024), 256, 0, stream>>>(Opart, Mpart, Lpart, Ob);
    out_proj_kernel<<<dim3(32, 8, BATCH), 256, 0, stream>>>(Ob, Wo, out);
}

// Round 5
// 164.817 us; speedup vs baseline: 1.4528x; 1.4528x over previous
//
#include <hip/hip_runtime.h>
#include <hip/hip_bf16.h>

#define S_LEN 4096
#define BATCH 4
#define DMODEL 1024
#define HDIM 128
#define NSLOT 4   // KV chunks per q-tile (equal split of the causal range)

typedef __attribute__((ext_vector_type(8))) short short8;
typedef __attribute__((ext_vector_type(4))) short short4v;
typedef __attribute__((ext_vector_type(4))) float float4v;
typedef __attribute__((ext_vector_type(16))) float float16v;
typedef __attribute__((ext_vector_type(4))) int int4v;

#define MASKVAL (-3.0e38f)
#define MINIT   (-1.0e30f)

static __device__ __forceinline__ unsigned short f2bf(float f) {
    __hip_bfloat16 h = __float2bfloat16(f);
    return *reinterpret_cast<unsigned short*>(&h);
}
static __device__ __forceinline__ unsigned short f2h(float f) {
    _Float16 h = (_Float16)f; return *reinterpret_cast<unsigned short*>(&h);
}
static __device__ __forceinline__ float h2f(unsigned short u) {
    _Float16 h = *reinterpret_cast<_Float16*>(&u); return (float)h;
}

// ---------------------------------------------------------------------------
// Kernel A: QKV projection, per-batch tiled.
// which=0 -> Q in (B,S,H) (scale folded in).
// which=1 -> K in MFMA A-fragment layout Kf[b][s/32][f=h/16][lane][e]:
//            Kf = K[b][kb32*32 + (lane&31)][f*16 + (lane>>5)*8 + e]
// which=2 -> V (operand-swapped MFMA -> V^T) in fragment layout
//            Vf[b][s/16][hb=h/32][lane][e] =
//            V[b][kt16*16 + (lane>>5)*8 + e][hb*32 + (lane&31)]
// ---------------------------------------------------------------------------
__global__ __launch_bounds__(256) void qkv_proj_kernel(
    const float* __restrict__ x, const float* __restrict__ Wq,
    const float* __restrict__ Wk, const float* __restrict__ Wv,
    unsigned short* __restrict__ Qb, unsigned short* __restrict__ Kf,
    unsigned short* __restrict__ Vf)
{
    __shared__ unsigned short As[128 * 72];
    __shared__ unsigned short Bs[128 * 72];

    const int t = threadIdx.x;
    const int s0 = blockIdx.x * 128;
    const int b = blockIdx.y;
    const int which = blockIdx.z;
    const float* W = (which == 0) ? Wq : (which == 1) ? Wk : Wv;

    const int lane = t & 63;
    const int w = t >> 6;
    const int wr = (w >> 1) * 64;
    const int wc = (w & 1) * 64;
    const int l15 = lane & 15;
    const int l4 = lane >> 4;

    float4v acc[4][4];
#pragma unroll
    for (int i = 0; i < 4; i++)
#pragma unroll
        for (int j = 0; j < 4; j++) acc[i][j] = (float4v){0.f, 0.f, 0.f, 0.f};

    const int krow = t >> 4;
    const int kcol4 = (t & 15) * 4;

    for (int k0 = 0; k0 < DMODEL; k0 += 64) {
        __syncthreads();
#pragma unroll
        for (int p = 0; p < 8; p++) {
            int row = p * 16 + krow;
            float4 v = *reinterpret_cast<const float4*>(
                &x[((size_t)(s0 + row) * BATCH + b) * DMODEL + k0 + kcol4]);
            short4v h;
            h[0] = (short)f2bf(v.x); h[1] = (short)f2bf(v.y);
            h[2] = (short)f2bf(v.z); h[3] = (short)f2bf(v.w);
            *reinterpret_cast<short4v*>(&As[row * 72 + kcol4]) = h;
        }
#pragma unroll
        for (int p = 0; p < 8; p++) {
            int row = p * 16 + krow;
            float4 v = *reinterpret_cast<const float4*>(
                &W[(size_t)row * DMODEL + k0 + kcol4]);
            short4v h;
            h[0] = (short)f2bf(v.x); h[1] = (short)f2bf(v.y);
            h[2] = (short)f2bf(v.z); h[3] = (short)f2bf(v.w);
            *reinterpret_cast<short4v*>(&Bs[row * 72 + kcol4]) = h;
        }
        __syncthreads();

#pragma unroll
        for (int kk = 0; kk < 64; kk += 32) {
            short8 a[4], bfr[4];
#pragma unroll
            for (int mi = 0; mi < 4; mi++)
                a[mi] = *reinterpret_cast<const short8*>(
                    &As[(wr + mi * 16 + l15) * 72 + kk + l4 * 8]);
#pragma unroll
            for (int ni = 0; ni < 4; ni++)
                bfr[ni] = *reinterpret_cast<const short8*>(
                    &Bs[(wc + ni * 16 + l15) * 72 + kk + l4 * 8]);
            if (which != 2) {
#pragma unroll
                for (int mi = 0; mi < 4; mi++)
#pragma unroll
                    for (int ni = 0; ni < 4; ni++)
                        acc[mi][ni] = __builtin_amdgcn_mfma_f32_16x16x32_bf16(
                            a[mi], bfr[ni], acc[mi][ni], 0, 0, 0);
            } else {
#pragma unroll
                for (int mi = 0; mi < 4; mi++)
#pragma unroll
                    for (int ni = 0; ni < 4; ni++)
                        acc[mi][ni] = __builtin_amdgcn_mfma_f32_16x16x32_bf16(
                            bfr[ni], a[mi], acc[mi][ni], 0, 0, 0);
            }
        }
    }

    if (which == 0) {
        const float scale = 0.08838834764831845f;
#pragma unroll
        for (int mi = 0; mi < 4; mi++)
#pragma unroll
            for (int ni = 0; ni < 4; ni++)
#pragma unroll
                for (int r = 0; r < 4; r++) {
                    int s = s0 + wr + mi * 16 + l4 * 4 + r;
                    int h = wc + ni * 16 + l15;
                    Qb[((size_t)b * S_LEN + s) * HDIM + h] =
                        f2bf(acc[mi][ni][r] * scale);
                }
    } else if (which == 1) {
        // rows = K-row s, cols = h
#pragma unroll
        for (int mi = 0; mi < 4; mi++)
#pragma unroll
            for (int ni = 0; ni < 4; ni++)
#pragma unroll
                for (int r = 0; r < 4; r++) {
                    int s = s0 + wr + mi * 16 + l4 * 4 + r;
                    int h = wc + ni * 16 + l15;
                    size_t addr =
                        (((size_t)b * (S_LEN / 32) + (s >> 5)) * 8 + (h >> 4)) * 512
                        + (size_t)(((s & 31) + 32 * ((h >> 3) & 1)) * 8 + (h & 7));
                    Kf[addr] = f2bf(acc[mi][ni][r]);
                }
    } else {
        // rows = h (W rows), cols = s (x rows)
#pragma unroll
        for (int mi = 0; mi < 4; mi++)
#pragma unroll
            for (int ni = 0; ni < 4; ni++)
#pragma unroll
                for (int r = 0; r < 4; r++) {
                    int h = wc + ni * 16 + l4 * 4 + r;
                    int s = s0 + wr + mi * 16 + l15;
                    size_t addr =
                        (((size_t)b * (S_LEN / 16) + (s >> 4)) * 4 + (h >> 5)) * 512
                        + (size_t)(((h & 31) + 32 * ((s >> 3) & 1)) * 8 + (s & 7));
                    Vf[addr] = f2bf(acc[mi][ni][r]);
                }
    }
}

// ---------------------------------------------------------------------------
// Kernel B: causal flash attention — NO LDS, NO barriers.
// 4 independent waves x 32 q rows = 128 q rows per block.  KVBLK=64.
// K/V read directly from fragment-linear layouts (coalesced 1KB per load).
// Block decode is XCD-aware: batch pinned to 2 XCDs (K/V L2-resident),
// heavy q-tiles spread within each XCD.
// ---------------------------------------------------------------------------
__global__ __launch_bounds__(256) void attn_kernel(
    const unsigned short* __restrict__ Qb, const unsigned short* __restrict__ Kf,
    const unsigned short* __restrict__ Vf, unsigned short* __restrict__ Opart,
    float* __restrict__ Mpart, float* __restrict__ Lpart)
{
    const int t = threadIdx.x;
    const int w = t >> 6;             // wave 0..3
    const int lane = t & 63;
    const int l31 = lane & 31;
    const int hi = lane >> 5;         // 0/1 half

    // XCD-aware decode: xcd = blockIdx.x & 7 (2 per batch); p enumerates (qt,c)
    const int i = blockIdx.x;
    const int xx = i & 7, j = i >> 3;
    const int b = xx >> 1;
    const int p = j * 2 + (xx & 1);   // 0..127
    const int qt = 31 - (p & 31);
    const int c = p >> 5;

    const int nkv = 2 * (qt + 1);
    const int csize = (nkv + NSLOT - 1) / NSLOT;
    const int lo = c * csize;
    const int hic = min(lo + csize, nkv);
    if (lo >= hic) return;

    const int qb = qt * 128;
    const int qrow = qb + w * 32 + l31;       // this lane's q (col of S^T)

    // Q as B-fragments: qf[f] = Q[qrow][f*16 + hi*8 .. +7]
    const unsigned short* qp = &Qb[((size_t)b * S_LEN + qrow) * HDIM + hi * 8];
    short8 qf[8];
#pragma unroll
    for (int f = 0; f < 8; f++)
        qf[f] = *reinterpret_cast<const short8*>(qp + f * 16);

    // fragment base pointers (lane folded in)
    const unsigned short* kbase =
        Kf + (size_t)b * (S_LEN / 32) * 8 * 512 + lane * 8;
    const unsigned short* vbase =
        Vf + (size_t)b * (S_LEN / 16) * 4 * 512 + lane * 8;

    float m_run = MINIT, l_run = 0.f;
    float16v o[4];                    // O^T: rows h (4 blocks of 32), col q
#pragma unroll
    for (int hb = 0; hb < 4; hb++)
#pragma unroll
        for (int r = 0; r < 16; r++) o[hb][r] = 0.f;

    for (int ti = lo; ti < hic; ti++) {
        const int kvb = ti * 64;
        const unsigned short* kp = kbase + (size_t)ti * 8192;   // 2 kb32 * 8f * 512

        // S^T = K Q^T: s0 = kv 0..31 of tile, s1 = kv 32..63; col = q
        float16v s0, s1;
#pragma unroll
        for (int r = 0; r < 16; r++) { s0[r] = 0.f; s1[r] = 0.f; }
#pragma unroll
        for (int f = 0; f < 8; f++) {
            short8 k0 = *reinterpret_cast<const short8*>(kp + f * 512);
            short8 k1 = *reinterpret_cast<const short8*>(kp + 4096 + f * 512);
            s0 = __builtin_amdgcn_mfma_f32_32x32x16_bf16(k0, qf[f], s0, 0, 0, 0);
            s1 = __builtin_amdgcn_mfma_f32_32x32x16_bf16(k1, qf[f], s1, 0, 0, 0);
        }

        // causal mask (only tiles touching/above this wave's diagonal band)
        if (kvb + 63 > qb + w * 32) {
#pragma unroll
            for (int r = 0; r < 16; r++) {
                int kv0 = kvb + (r & 3) + 8 * (r >> 2) + 4 * hi;
                if (kv0 > qrow) s0[r] = MASKVAL;
                if (kv0 + 32 > qrow) s1[r] = MASKVAL;
            }
        }

        // in-register softmax over this lane's 32 kv + pair-lane combine
        float pmax = s0[0];
#pragma unroll
        for (int r = 1; r < 16; r++) pmax = fmaxf(pmax, s0[r]);
#pragma unroll
        for (int r = 0; r < 16; r++) pmax = fmaxf(pmax, s1[r]);
        pmax = fmaxf(pmax, __shfl_xor(pmax, 32));
        float mnew = fmaxf(m_run, pmax);
        float alpha = __expf(m_run - mnew);
        m_run = mnew;
#pragma unroll
        for (int r = 0; r < 16; r++) s0[r] = __expf(s0[r] - mnew);
#pragma unroll
        for (int r = 0; r < 16; r++) s1[r] = __expf(s1[r] - mnew);
        float sum = 0.f;
#pragma unroll
        for (int r = 0; r < 16; r++) sum += s0[r] + s1[r];
        sum += __shfl_xor(sum, 32);
        l_run = l_run * alpha + sum;
#pragma unroll
        for (int hb = 0; hb < 4; hb++) o[hb] = o[hb] * alpha;

        // PV: O^T += V^T @ P  (P as B-operand, built in-register per window)
        const unsigned short* vp = vbase + (size_t)ti * 8192;   // 4 kt16 * 4 hb * 512
#pragma unroll
        for (int tw = 0; tw < 4; tw++) {
            float pv[8];
#pragma unroll
            for (int jj = 0; jj < 8; jj++)
                pv[jj] = (tw < 2) ? ((tw & 1) ? s0[8 + jj] : s0[jj])
                                  : ((tw & 1) ? s1[8 + jj] : s1[jj]);
            unsigned int A  = (unsigned int)f2bf(pv[0]) | ((unsigned int)f2bf(pv[1]) << 16);
            unsigned int Bw = (unsigned int)f2bf(pv[2]) | ((unsigned int)f2bf(pv[3]) << 16);
            unsigned int C  = (unsigned int)f2bf(pv[4]) | ((unsigned int)f2bf(pv[5]) << 16);
            unsigned int D  = (unsigned int)f2bf(pv[6]) | ((unsigned int)f2bf(pv[7]) << 16);
            // exchange: each lane sends what its partner needs
            unsigned int y1 = (unsigned int)__shfl_xor((int)(hi ? A : C), 32);
            unsigned int y2 = (unsigned int)__shfl_xor((int)(hi ? Bw : D), 32);
            int4v pw;
            pw[0] = (int)(hi ? y1 : A);
            pw[1] = (int)(hi ? y2 : Bw);
            pw[2] = (int)(hi ? C : y1);
            pw[3] = (int)(hi ? D : y2);
            union { int4v iv; short8 s; } pu; pu.iv = pw;
#pragma unroll
            for (int hb = 0; hb < 4; hb++) {
                short8 vf = *reinterpret_cast<const short8*>(
                    vp + (tw * 4 + hb) * 512);
                o[hb] = __builtin_amdgcn_mfma_f32_32x32x16_bf16(vf, pu.s, o[hb], 0, 0, 0);
            }
        }
    }

    // epilogue: normalized fp16 partial + (m,l);  l==0 -> zeros (fully masked)
    const size_t R0 = (size_t)(c * BATCH + b) * S_LEN;
    const float inv = (l_run > 0.f) ? 1.f / l_run : 0.f;
#pragma unroll
    for (int hb = 0; hb < 4; hb++)
#pragma unroll
        for (int g = 0; g < 4; g++) {
            int h0 = hb * 32 + g * 8 + hi * 4;
            short4v ov;
#pragma unroll
            for (int jj = 0; jj < 4; jj++)
                ov[jj] = (short)f2h(o[hb][g * 4 + jj] * inv);
            *reinterpret_cast<short4v*>(&Opart[(R0 + qrow) * HDIM + h0]) = ov;
        }
    if (hi == 0) { Mpart[R0 + qrow] = m_run; Lpart[R0 + qrow] = l_run; }
}

// ---------------------------------------------------------------------------
// Kernel B2: combine partials -> Ob (B,S,H) bf16
// ---------------------------------------------------------------------------
__global__ __launch_bounds__(256) void combine_kernel(
    const unsigned short* __restrict__ Opart, const float* __restrict__ Mpart,
    const float* __restrict__ Lpart, unsigned short* __restrict__ Ob)
{
    const int BS = BATCH * S_LEN;
    int idx = blockIdx.x * 256 + threadIdx.x;
    int r = idx >> 4, hc = (idx & 15) * 8;
    int q = r & (S_LEN - 1);
    int qt = q >> 7;
    int nkv = 2 * (qt + 1);
    int csize = (nkv + NSLOT - 1) / NSLOT;
    int cnt = (nkv + csize - 1) / csize;     // # non-empty chunks

    float m = -INFINITY;
    for (int j = 0; j < cnt; j++) m = fmaxf(m, Mpart[j * BS + r]);
    float wsum = 0.f;
    float acc[8];
#pragma unroll
    for (int e = 0; e < 8; e++) acc[e] = 0.f;
    for (int j = 0; j < cnt; j++) {
        float wj = __expf(Mpart[j * BS + r] - m) * Lpart[j * BS + r];
        wsum += wj;
        short8 o = *reinterpret_cast<const short8*>(
            &Opart[((size_t)j * BS + r) * HDIM + hc]);
#pragma unroll
        for (int e = 0; e < 8; e++) acc[e] += wj * h2f((unsigned short)o[e]);
    }
    float inv = 1.f / wsum;
    short8 ob;
#pragma unroll
    for (int e = 0; e < 8; e++) ob[e] = (short)f2bf(acc[e] * inv);
    *reinterpret_cast<short8*>(&Ob[(size_t)r * HDIM + hc]) = ob;
}

// ---------------------------------------------------------------------------
// Kernel C: output projection, per-batch tiled.
// ---------------------------------------------------------------------------
__global__ __launch_bounds__(256) void out_proj_kernel(
    const unsigned short* __restrict__ Ob, const float* __restrict__ Wo,
    float* __restrict__ out)
{
    __shared__ unsigned short As[128 * 128];
    __shared__ unsigned short Bs[128 * 128];

    const int t = threadIdx.x;
    const int lane = t & 63, w = t >> 6;
    const int l15 = lane & 15, l4 = lane >> 4;
    const int wr = (w >> 1) * 64, wc = (w & 1) * 64;
    const int s0 = blockIdx.x * 128;
    const int d0 = blockIdx.y * 128;
    const int b = blockIdx.z;

#pragma unroll
    for (int p = 0; p < 8; p++) {
        int e = p * 2048 + t * 8;
        int r = e >> 7, h = e & 127;
        short8 v = *reinterpret_cast<const short8*>(
            &Ob[((size_t)b * S_LEN + s0 + r) * HDIM + h]);
        int off = (r * 256 + h * 2) ^ ((r & 7) << 4);
        *reinterpret_cast<short8*>(reinterpret_cast<char*>(As) + off) = v;
    }
#pragma unroll
    for (int p = 0; p < 16; p++) {
        int e = p * 1024 + t * 4;
        int r = e >> 7, h = e & 127;
        float4 v = *reinterpret_cast<const float4*>(&Wo[(size_t)(d0 + r) * HDIM + h]);
        short4v hh;
        hh[0] = (short)f2bf(v.x); hh[1] = (short)f2bf(v.y);
        hh[2] = (short)f2bf(v.z); hh[3] = (short)f2bf(v.w);
        int off = (r * 256 + h * 2) ^ ((r & 7) << 4);
        *reinterpret_cast<short4v*>(reinterpret_cast<char*>(Bs) + off) = hh;
    }
    __syncthreads();

    float4v acc[4][4];
#pragma unroll
    for (int i = 0; i < 4; i++)
#pragma unroll
        for (int j = 0; j < 4; j++) acc[i][j] = (float4v){0.f, 0.f, 0.f, 0.f};

#pragma unroll
    for (int kk = 0; kk < 4; kk++) {
        short8 a[4], bf[4];
#pragma unroll
        for (int mi = 0; mi < 4; mi++) {
            int row = wr + mi * 16 + l15;
            int off = (row * 256 + (kk * 32 + l4 * 8) * 2) ^ ((row & 7) << 4);
            a[mi] = *reinterpret_cast<const short8*>(
                reinterpret_cast<const char*>(As) + off);
        }
#pragma unroll
        for (int ni = 0; ni < 4; ni++) {
            int row = wc + ni * 16 + l15;
            int off = (row * 256 + (kk * 32 + l4 * 8) * 2) ^ ((row & 7) << 4);
            bf[ni] = *reinterpret_cast<const short8*>(
                reinterpret_cast<const char*>(Bs) + off);
        }
#pragma unroll
        for (int mi = 0; mi < 4; mi++)
#pragma unroll
            for (int ni = 0; ni < 4; ni++)
                acc[mi][ni] = __builtin_amdgcn_mfma_f32_16x16x32_bf16(
                    a[mi], bf[ni], acc[mi][ni], 0, 0, 0);
    }

#pragma unroll
    for (int mi = 0; mi < 4; mi++)
#pragma unroll
        for (int ni = 0; ni < 4; ni++)
#pragma unroll
            for (int r = 0; r < 4; r++) {
                int s = s0 + wr + mi * 16 + l4 * 4 + r;
                int d = d0 + wc + ni * 16 + l15;
                out[((size_t)s * BATCH + b) * DMODEL + d] = acc[mi][ni][r];
            }
}

// ---------------------------------------------------------------------------
extern "C" void kernel_launch(void* const* d_in, const int* in_sizes, int n_in,
                              void* d_out, int out_size, void* d_ws, size_t ws_size,
                              hipStream_t stream) {
    const float* x  = (const float*)d_in[0];
    const float* Wq = (const float*)d_in[1];
    const float* Wk = (const float*)d_in[2];
    const float* Wv = (const float*)d_in[3];
    const float* Wo = (const float*)d_in[4];
    float* out = (float*)d_out;

    const size_t elems = (size_t)BATCH * S_LEN * HDIM;     // 2M
    const size_t BS = (size_t)BATCH * S_LEN;               // 16384
    unsigned short* Qb    = (unsigned short*)d_ws;
    unsigned short* Kf    = Qb + elems;
    unsigned short* Vf    = Kf + elems;
    unsigned short* Ob    = Vf + elems;
    unsigned short* Opart = Ob + elems;                    // NSLOT*BS*H fp16
    float* Mpart = (float*)(Opart + (size_t)NSLOT * BS * HDIM);
    float* Lpart = Mpart + (size_t)NSLOT * BS;

    qkv_proj_kernel<<<dim3(32, BATCH, 3), 256, 0, stream>>>(x, Wq, Wk, Wv, Qb, Kf, Vf);
    attn_kernel<<<dim3(512), 256, 0, stream>>>(Qb, Kf, Vf, Opart, Mpart, Lpart);
    combine_kernel<<<dim3(1024), 256, 0, stream>>>(Opart, Mpart, Lpart, Ob);
    out_proj_kernel<<<dim3(32, 8, BATCH), 256, 0, stream>>>(Ob, Wo, out);
}